// Round 6
// baseline (102.835 us; speedup 1.0000x reference)
//
#include <hip/hip_runtime.h>
#include <hip/hip_bf16.h>
#include <stdint.h>

#define HD 768

typedef __attribute__((ext_vector_type(8))) short bf16x8;
typedef __attribute__((ext_vector_type(4))) float f32x4;

__device__ inline unsigned short f2bf(float f) {
  union { float f; unsigned int u; } v; v.f = f;
  return (unsigned short)((v.u + 0x7fffu + ((v.u >> 16) & 1u)) >> 16);
}
__device__ inline float bf2f(unsigned short u) {
  union { unsigned int uu; float f; } v; v.uu = ((unsigned int)u) << 16;
  return v.f;
}

#define LGKM(N) { asm volatile("s_waitcnt lgkmcnt(" #N ")" ::: "memory"); __builtin_amdgcn_sched_barrier(0); }
#define VMC(N) { asm volatile("s_waitcnt vmcnt(" #N ")" ::: "memory"); __builtin_amdgcn_sched_barrier(0); }

// ---------------- prep: pack Gw and Ow into MFMA B-fragments + monarch frags ----------------
// bid [0,288) Gpk; [288,576) Opk; [576,600) w1f; [600,612) w2f.
__global__ void prep_kernel(const float* __restrict__ gw, const float* __restrict__ ow,
                            const float* __restrict__ w1, const float* __restrict__ w2,
                            unsigned short* __restrict__ Gpk,
                            unsigned short* __restrict__ Opk,
                            unsigned short* __restrict__ w1f,
                            unsigned short* __restrict__ w2f) {
  int bid = blockIdx.x;
  if (bid < 576) {
    // B-fragment pack: 16B chunk r = (nt*24+ks)*64+lane;
    // lane = lr + 16*lg holds W[nt*16+lr][ks*32 + lg*8 .. +7]
    const float* src = (bid < 288) ? gw : ow;
    unsigned short* dst = (bid < 288) ? Gpk : Opk;
    int r = ((bid < 288) ? bid : bid - 288) * 256 + threadIdx.x;   // 73728
    int lane = r & 63;
    int ks = (r >> 6) % 24;
    int nt = r / (24 * 64);
    int n = nt * 16 + (lane & 15);
    int k = ks * 32 + (lane >> 4) * 8;
    bf16x8 pack;
#pragma unroll
    for (int j = 0; j < 8; ++j) pack[j] = (short)f2bf(src[(size_t)n * HD + k + j]);
    *(bf16x8*)(dst + (size_t)r * 8) = pack;
  } else if (bid < 600) {
    // w1 B-frags: fi = (k*3+nt)*2+ks; B[q=nt*16+lr][kk=ks*32+lg*8+j] = w1[k][kk][q], kk<48 else 0
    int e = (bid - 576) * 256 + threadIdx.x;   // 6144
    int lane = e & 63, fi = e >> 6;
    int ks = fi & 1, nt = (fi >> 1) % 3, k = fi / 6;
    int lrr = lane & 15, lgg = lane >> 4;
    int q = nt * 16 + lrr;
    bf16x8 pack;
#pragma unroll
    for (int j = 0; j < 8; ++j) {
      int kk = ks * 32 + lgg * 8 + j;
      float v = (kk < 48) ? w1[(k * 48 + kk) * 48 + q] : 0.0f;
      pack[j] = (short)f2bf(v);
    }
    *(bf16x8*)(w1f + (size_t)e * 8) = pack;
  } else {
    // w2 B-frags: one per q; B[k2=lr][kk=lg*8+j] = w2[q][kk][k2], kk<16 else 0
    int e = (bid - 600) * 256 + threadIdx.x;   // 3072
    int lane = e & 63, q = e >> 6;
    int lrr = lane & 15, lgg = lane >> 4;
    bf16x8 pack;
#pragma unroll
    for (int j = 0; j < 8; ++j) {
      int kk = lgg * 8 + j;
      float v = (kk < 16) ? w2[(q * 16 + kk) * 16 + lrr] : 0.0f;
      pack[j] = (short)f2bf(v);
    }
    *(bf16x8*)(w2f + (size_t)e * 8) = pack;
  }
}

// ---------------- fused: out = LN((sig(x@Gw^T+gb) . monarch(x)) @ Ow^T + ob + x) ----------------
// 256 blocks (1/CU) x 512 thr (8 waves). Block owns 64 rows end-to-end.
// LDS: tile 96KB (x bf16 -> h bf16), scratch 48KB (monarch z/mixed 32-row halves), psums 4KB.
// GEMM loops: A resident in LDS, B streamed as packed reg-fragments (dbuf) -> NO barriers.
__global__ __launch_bounds__(512, 2)
void fused_kernel(const float* __restrict__ x,
                  const unsigned short* __restrict__ Gpk,
                  const unsigned short* __restrict__ Opk,
                  const unsigned short* __restrict__ w1f,
                  const unsigned short* __restrict__ w2f,
                  const float* __restrict__ gate_b,
                  const float* __restrict__ out_b,
                  const float* __restrict__ gamma,
                  const float* __restrict__ beta,
                  float* __restrict__ out) {
  __shared__ __align__(16) unsigned char tile[98304];    // 64 x 768 bf16, swizzled
  __shared__ __align__(16) unsigned char scratch[49152]; // 32 x 768 bf16 (z / mixed32)
  __shared__ float psum[64][8];
  __shared__ float psq[64][8];

  const int tid = threadIdx.x, lane = tid & 63, wid = tid >> 6;
  const int lr = lane & 15, lg = lane >> 4;
  const size_t m0 = (size_t)blockIdx.x * 64;

  // per-wave column biases (cols wid*96 + nt*16 + lr)
  float gbv[6], obv[6];
#pragma unroll
  for (int nt = 0; nt < 6; ++nt) {
    int col = wid * 96 + nt * 16 + lr;
    gbv[nt] = gate_b[col];
    obv[nt] = out_b[col];
  }

  // ---- P0: x fp32 -> tile bf16 (coalesced read, swizzled LDS write) ----
  {
    const float4* xs = (const float4*)x + m0 * 192;      // 12288 float4
#pragma unroll
    for (int p = 0; p < 24; ++p) {
      int id = p * 512 + tid;
      float4 v = xs[id];
      int row = id / 192, c4 = id - row * 192;
      uint2 u;
      u.x = (unsigned int)f2bf(v.x) | ((unsigned int)f2bf(v.y) << 16);
      u.y = (unsigned int)f2bf(v.z) | ((unsigned int)f2bf(v.w) << 16);
      *(uint2*)(tile + row * 1536 + ((c4 * 8) ^ ((row & 7) << 4))) = u;
    }
  }
  __syncthreads();

  // ---- GEMM machinery (A from resident tile, B from packed frags, reg dbuf) ----
  const int sx0 = (lg * 16) ^ ((lr & 7) << 4);
  const unsigned char* baA0 = tile + lr * 1536 + sx0;
  const unsigned char* baA1 = tile + lr * 1536 + (sx0 ^ 64);
  const unsigned short* gB = Gpk + ((size_t)(wid * 6) * 24 * 64 + lane) * 8;
  const unsigned short* oB = Opk + ((size_t)(wid * 6) * 24 * 64 + lane) * 8;

  bf16x8 aF0[4], aF1[4];
  bf16x8 bP[12], bQ[12];

#define LOAD_B(BB, KT, BR) { _Pragma("unroll") for (int nt = 0; nt < 6; ++nt) { \
      BR[nt * 2 + 0] = *(const bf16x8*)((BB) + nt * 12288 + ((KT) * 2 + 0) * 512); \
      BR[nt * 2 + 1] = *(const bf16x8*)((BB) + nt * 12288 + ((KT) * 2 + 1) * 512); } }
#define RD_A(KT) { _Pragma("unroll") for (int mt = 0; mt < 4; ++mt) { \
      aF0[mt] = *(const bf16x8*)(baA0 + mt * 24576 + (KT) * 128); \
      aF1[mt] = *(const bf16x8*)(baA1 + mt * 24576 + (KT) * 128); } }
#define MM48(ACC, BR) { __builtin_amdgcn_s_setprio(1); \
    _Pragma("unroll") for (int mt = 0; mt < 4; ++mt) \
    _Pragma("unroll") for (int nt = 0; nt < 6; ++nt) { \
      ACC[mt][nt] = __builtin_amdgcn_mfma_f32_16x16x32_bf16(aF0[mt], BR[nt * 2 + 0], ACC[mt][nt], 0, 0, 0); \
      ACC[mt][nt] = __builtin_amdgcn_mfma_f32_16x16x32_bf16(aF1[mt], BR[nt * 2 + 1], ACC[mt][nt], 0, 0, 0); } \
    __builtin_amdgcn_s_setprio(0); }
#define GEMM_LOOP(BB, ACC) { \
    LOAD_B(BB, 0, bP); \
    _Pragma("unroll 1") \
    for (int kt = 0; kt < 10; kt += 2) { \
      LOAD_B(BB, kt + 1, bQ); RD_A(kt); LGKM(0); VMC(12); MM48(ACC, bP); \
      LOAD_B(BB, kt + 2, bP); RD_A(kt + 1); LGKM(0); VMC(12); MM48(ACC, bQ); \
    } \
    LOAD_B(BB, 11, bQ); RD_A(10); LGKM(0); VMC(12); MM48(ACC, bP); \
    RD_A(11); LGKM(0); VMC(0); MM48(ACC, bQ); }

  // ---- P1: gate GEMM: accG = x @ Gw^T (per wave: 64 rows x 96 cols) ----
  f32x4 accG[4][6];
#pragma unroll
  for (int mt = 0; mt < 4; ++mt)
#pragma unroll
    for (int nt = 0; nt < 6; ++nt) accG[mt][nt] = (f32x4){0, 0, 0, 0};
  GEMM_LOOP(gB, accG);

  // ---- P3: monarch (2x 32-row halves) + h combine + accO(residual+ob) init ----
  f32x4 accO[4][6];

#define MONARCH_HALF(H) { \
    /* stage1: wave handles k = wid*2 + kb; z32 -> scratch */ \
    _Pragma("unroll") for (int kb = 0; kb < 2; ++kb) { \
      const int k = wid * 2 + kb; \
      const unsigned short* wf = w1f + (size_t)(k * 6) * 512 + lane * 8; \
      bf16x8 w1b0 = *(const bf16x8*)(wf + 0 * 512); \
      bf16x8 w1b1 = *(const bf16x8*)(wf + 1 * 512); \
      bf16x8 w1b2 = *(const bf16x8*)(wf + 2 * 512); \
      bf16x8 w1b3 = *(const bf16x8*)(wf + 3 * 512); \
      bf16x8 w1b4 = *(const bf16x8*)(wf + 4 * 512); \
      bf16x8 w1b5 = *(const bf16x8*)(wf + 5 * 512); \
      _Pragma("unroll") for (int mtl = 0; mtl < 2; ++mtl) { \
        const int row = (H) * 32 + mtl * 16 + lr; \
        const int rsw = (lr & 7) << 4; \
        bf16x8 a0 = *(const bf16x8*)(tile + row * 1536 + ((k * 96 + lg * 16) ^ rsw)); \
        bf16x8 a1 = (bf16x8){0, 0, 0, 0, 0, 0, 0, 0}; \
        if (lg < 2) a1 = *(const bf16x8*)(tile + row * 1536 + ((k * 96 + 64 + lg * 16) ^ rsw)); \
        f32x4 c0 = {0,0,0,0}, c1 = {0,0,0,0}, c2 = {0,0,0,0}; \
        c0 = __builtin_amdgcn_mfma_f32_16x16x32_bf16(a0, w1b0, c0, 0, 0, 0); \
        c0 = __builtin_amdgcn_mfma_f32_16x16x32_bf16(a1, w1b1, c0, 0, 0, 0); \
        c1 = __builtin_amdgcn_mfma_f32_16x16x32_bf16(a0, w1b2, c1, 0, 0, 0); \
        c1 = __builtin_amdgcn_mfma_f32_16x16x32_bf16(a1, w1b3, c1, 0, 0, 0); \
        c2 = __builtin_amdgcn_mfma_f32_16x16x32_bf16(a0, w1b4, c2, 0, 0, 0); \
        c2 = __builtin_amdgcn_mfma_f32_16x16x32_bf16(a1, w1b5, c2, 0, 0, 0); \
        _Pragma("unroll") for (int i = 0; i < 4; ++i) { \
          int rl = mtl * 16 + lg * 4 + i; \
          int zsw = (rl & 7) << 4; \
          *(unsigned short*)(scratch + ((rl * 1536 + 0 * 512 + lr * 32 + k * 2) ^ zsw)) = f2bf(c0[i]); \
          *(unsigned short*)(scratch + ((rl * 1536 + 1 * 512 + lr * 32 + k * 2) ^ zsw)) = f2bf(c1[i]); \
          *(unsigned short*)(scratch + ((rl * 1536 + 2 * 512 + lr * 32 + k * 2) ^ zsw)) = f2bf(c2[i]); } } } \
    __syncthreads(); \
    /* stage2: wave handles q = wid*6 + qq (8 waves x 6 = 48); u packed in regs */ \
    { unsigned int upk[2][4][3]; \
    _Pragma("unroll") for (int qq = 0; qq < 6; ++qq) { \
      const int q = wid * 6 + qq; \
      bf16x8 bw = *(const bf16x8*)(w2f + (size_t)q * 512 + lane * 8); \
      _Pragma("unroll") for (int mtl = 0; mtl < 2; ++mtl) { \
        int rl = mtl * 16 + lr; \
        bf16x8 a = (bf16x8){0, 0, 0, 0, 0, 0, 0, 0}; \
        if (lg < 2) a = *(const bf16x8*)(scratch + ((rl * 1536 + q * 32 + lg * 16) ^ ((rl & 7) << 4))); \
        f32x4 c = {0, 0, 0, 0}; \
        c = __builtin_amdgcn_mfma_f32_16x16x32_bf16(a, bw, c, 0, 0, 0); \
        _Pragma("unroll") for (int i = 0; i < 4; ++i) { \
          unsigned int h = (unsigned int)f2bf(c[i]); \
          if (qq & 1) upk[mtl][i][qq >> 1] |= (h << 16); \
          else        upk[mtl][i][qq >> 1] = h; } } } \
    __syncthreads();  /* z reads done; scratch reusable */ \
    /* mixed32 row-major bf16 into scratch: u[rl][n = lr*48 + wid*6 + qq] */ \
    _Pragma("unroll") for (int mtl = 0; mtl < 2; ++mtl) \
    _Pragma("unroll") for (int i = 0; i < 4; ++i) { \
      int rl = mtl * 16 + lg * 4 + i; \
      int base = rl * 1536 + lr * 96 + wid * 12; \
      int msw = (rl & 7) << 4; \
      _Pragma("unroll") for (int p = 0; p < 3; ++p) \
        *(unsigned int*)(scratch + ((base + p * 4) ^ msw)) = upk[mtl][i][p]; } } \
    __syncthreads(); \
    /* accO init (residual + ob from tile/x) then h overwrites tile */ \
    _Pragma("unroll") for (int mtl = 0; mtl < 2; ++mtl) \
    _Pragma("unroll") for (int nt = 0; nt < 6; ++nt) \
    _Pragma("unroll") for (int i = 0; i < 4; ++i) { \
      int rl = mtl * 16 + lg * 4 + i; \
      int row = (H) * 32 + rl; \
      int colb = (wid * 96 + nt * 16 + lr) * 2; \
      float mval = bf2f(*(const unsigned short*)(scratch + ((rl * 1536 + colb) ^ ((rl & 7) << 4)))); \
      float g = accG[(H) * 2 + mtl][nt][i] + gbv[nt]; \
      float s = 1.0f / (1.0f + __expf(-g)); \
      unsigned char* tp = tile + row * 1536 + (colb ^ ((row & 7) << 4)); \
      accO[(H) * 2 + mtl][nt][i] = bf2f(*(const unsigned short*)tp) + obv[nt]; \
      *(unsigned short*)tp = f2bf(s * mval); } \
    __syncthreads(); }

  MONARCH_HALF(0)
  MONARCH_HALF(1)

  // ---- P4: out GEMM: accO += h @ Ow^T (tile now holds h) ----
  GEMM_LOOP(oB, accO);

  // ---- P5: LayerNorm + fp32 store ----
#pragma unroll
  for (int mt = 0; mt < 4; ++mt) {
#pragma unroll
    for (int i = 0; i < 4; ++i) {
      float s = 0.f, q = 0.f;
#pragma unroll
      for (int nt = 0; nt < 6; ++nt) { float v = accO[mt][nt][i]; s += v; q += v * v; }
#pragma unroll
      for (int off = 8; off >= 1; off >>= 1) {
        s += __shfl_xor(s, off);
        q += __shfl_xor(q, off);
      }
      if (lr == 0) {
        int rl = mt * 16 + lg * 4 + i;
        psum[rl][wid] = s; psq[rl][wid] = q;
      }
    }
  }
  __syncthreads();
#pragma unroll
  for (int mt = 0; mt < 4; ++mt) {
#pragma unroll
    for (int i = 0; i < 4; ++i) {
      int rl = mt * 16 + lg * 4 + i;
      float s = 0.f, q = 0.f;
#pragma unroll
      for (int w = 0; w < 8; ++w) { s += psum[rl][w]; q += psq[rl][w]; }
      float mu = s * (1.0f / 768.0f);
      float var = q * (1.0f / 768.0f) - mu * mu;
      var = var < 0.f ? 0.f : var;
      float rstd = rsqrtf(var + 1e-12f);
      size_t grow = m0 + rl;
#pragma unroll
      for (int nt = 0; nt < 6; ++nt) {
        int col = wid * 96 + nt * 16 + lr;
        out[grow * 768 + col] = (accO[mt][nt][i] - mu) * rstd * gamma[col] + beta[col];
      }
    }
  }
#undef LOAD_B
#undef RD_A
#undef MM48
#undef GEMM_LOOP
#undef MONARCH_HALF
}

// ---------------- launch ----------------
extern "C" void kernel_launch(void* const* d_in, const int* in_sizes, int n_in,
                              void* d_out, int out_size, void* d_ws, size_t ws_size,
                              hipStream_t stream) {
  const float* x   = (const float*)d_in[0];
  const float* w1  = (const float*)d_in[1];
  const float* w2  = (const float*)d_in[2];
  const float* gw  = (const float*)d_in[3];
  const float* gb  = (const float*)d_in[4];
  const float* ow  = (const float*)d_in[5];
  const float* ob  = (const float*)d_in[6];
  const float* gam = (const float*)d_in[7];
  const float* bet = (const float*)d_in[8];
  float* out = (float*)d_out;

  char* ws = (char*)d_ws;
  unsigned short* Gpk = (unsigned short*)(ws);                   // 1,179,648 B
  unsigned short* Opk = (unsigned short*)(ws + 1179648);         // 1,179,648 B
  unsigned short* w1f = (unsigned short*)(ws + 2359296);         //    98,304 B
  unsigned short* w2f = (unsigned short*)(ws + 2457600);         //    49,152 B

  prep_kernel<<<612, 256, 0, stream>>>(gw, ow, w1, w2, Gpk, Opk, w1f, w2f);
  fused_kernel<<<256, 512, 0, stream>>>(x, Gpk, Opk, w1f, w2f, gb, ob, gam, bet, out);
}

// Round 7
// 102.792 us; speedup vs baseline: 1.0004x; 1.0004x over previous
//
#include <hip/hip_runtime.h>
#include <hip/hip_bf16.h>
#include <stdint.h>

#define HD 768

typedef __attribute__((ext_vector_type(8))) short bf16x8;
typedef __attribute__((ext_vector_type(4))) float f32x4;

__device__ inline unsigned short f2bf(float f) {
  union { float f; unsigned int u; } v; v.f = f;
  return (unsigned short)((v.u + 0x7fffu + ((v.u >> 16) & 1u)) >> 16);
}
__device__ inline float bf2f(unsigned short u) {
  union { unsigned int uu; float f; } v; v.uu = ((unsigned int)u) << 16;
  return v.f;
}

#define LGKM(N) { asm volatile("s_waitcnt lgkmcnt(" #N ")" ::: "memory"); __builtin_amdgcn_sched_barrier(0); }
#define VMC(N) { asm volatile("s_waitcnt vmcnt(" #N ")" ::: "memory"); __builtin_amdgcn_sched_barrier(0); }

// ---------------- prep: pack Gw and Ow into MFMA B-fragments + monarch frags ----------------
// bid [0,288) Gpk; [288,576) Opk; [576,600) w1f; [600,612) w2f.
__global__ void prep_kernel(const float* __restrict__ gw, const float* __restrict__ ow,
                            const float* __restrict__ w1, const float* __restrict__ w2,
                            unsigned short* __restrict__ Gpk,
                            unsigned short* __restrict__ Opk,
                            unsigned short* __restrict__ w1f,
                            unsigned short* __restrict__ w2f) {
  int bid = blockIdx.x;
  if (bid < 576) {
    // B-fragment pack: 16B chunk r = (nt*24+ks)*64+lane;
    // lane = lr + 16*lg holds W[nt*16+lr][ks*32 + lg*8 .. +7]
    const float* src = (bid < 288) ? gw : ow;
    unsigned short* dst = (bid < 288) ? Gpk : Opk;
    int r = ((bid < 288) ? bid : bid - 288) * 256 + threadIdx.x;   // 73728
    int lane = r & 63;
    int ks = (r >> 6) % 24;
    int nt = r / (24 * 64);
    int n = nt * 16 + (lane & 15);
    int k = ks * 32 + (lane >> 4) * 8;
    bf16x8 pack;
#pragma unroll
    for (int j = 0; j < 8; ++j) pack[j] = (short)f2bf(src[(size_t)n * HD + k + j]);
    *(bf16x8*)(dst + (size_t)r * 8) = pack;
  } else if (bid < 600) {
    // w1 B-frags: fi = (k*3+nt)*2+ks; B[q=nt*16+lr][kk=ks*32+lg*8+j] = w1[k][kk][q], kk<48 else 0
    int e = (bid - 576) * 256 + threadIdx.x;   // 6144
    int lane = e & 63, fi = e >> 6;
    int ks = fi & 1, nt = (fi >> 1) % 3, k = fi / 6;
    int lrr = lane & 15, lgg = lane >> 4;
    int q = nt * 16 + lrr;
    bf16x8 pack;
#pragma unroll
    for (int j = 0; j < 8; ++j) {
      int kk = ks * 32 + lgg * 8 + j;
      float v = (kk < 48) ? w1[(k * 48 + kk) * 48 + q] : 0.0f;
      pack[j] = (short)f2bf(v);
    }
    *(bf16x8*)(w1f + (size_t)e * 8) = pack;
  } else {
    // w2 B-frags: one per q; B[k2=lr][kk=lg*8+j] = w2[q][kk][k2], kk<16 else 0
    int e = (bid - 600) * 256 + threadIdx.x;   // 3072
    int lane = e & 63, q = e >> 6;
    int lrr = lane & 15, lgg = lane >> 4;
    bf16x8 pack;
#pragma unroll
    for (int j = 0; j < 8; ++j) {
      int kk = lgg * 8 + j;
      float v = (kk < 16) ? w2[(q * 16 + kk) * 16 + lrr] : 0.0f;
      pack[j] = (short)f2bf(v);
    }
    *(bf16x8*)(w2f + (size_t)e * 8) = pack;
  }
}

// ---------------- fused: out = LN((sig(x@Gw^T+gb) . monarch(x)) @ Ow^T + ob + x) ----------------
// 256 blocks (1/CU) x 512 thr (8 waves). Block owns 64 rows end-to-end.
// LDS: tile 96KB (x bf16 -> h bf16), scratch 48KB (monarch z/mixed), psums 4KB = 151.5KB
// -> 1 block/CU regardless, so min-waves-per-EU = 1 (256-VGPR budget; the ",2" in R6
//    capped VGPRs at 128 and spilled both 96-reg accumulators to scratch/HBM:
//    WRITE_SIZE 119.8MB vs 50.3 ideal, FETCH 69.5 vs 52, MfmaUtil 9.6%).
__global__ __launch_bounds__(512, 1)
void fused_kernel(const float* __restrict__ x,
                  const unsigned short* __restrict__ Gpk,
                  const unsigned short* __restrict__ Opk,
                  const unsigned short* __restrict__ w1f,
                  const unsigned short* __restrict__ w2f,
                  const float* __restrict__ gate_b,
                  const float* __restrict__ out_b,
                  const float* __restrict__ gamma,
                  const float* __restrict__ beta,
                  float* __restrict__ out) {
  __shared__ __align__(16) unsigned char tile[98304];    // 64 x 768 bf16, swizzled
  __shared__ __align__(16) unsigned char scratch[49152]; // 32 x 768 bf16 (z / mixed32)
  __shared__ float psum[64][8];
  __shared__ float psq[64][8];

  const int tid = threadIdx.x, lane = tid & 63, wid = tid >> 6;
  const int lr = lane & 15, lg = lane >> 4;
  const size_t m0 = (size_t)blockIdx.x * 64;

  // per-wave column biases (cols wid*96 + nt*16 + lr)
  float gbv[6], obv[6];
#pragma unroll
  for (int nt = 0; nt < 6; ++nt) {
    int col = wid * 96 + nt * 16 + lr;
    gbv[nt] = gate_b[col];
    obv[nt] = out_b[col];
  }

  // ---- P0: x fp32 -> tile bf16 (coalesced read, swizzled LDS write) ----
  {
    const float4* xs = (const float4*)x + m0 * 192;      // 12288 float4
#pragma unroll
    for (int p = 0; p < 24; ++p) {
      int id = p * 512 + tid;
      float4 v = xs[id];
      int row = id / 192, c4 = id - row * 192;
      uint2 u;
      u.x = (unsigned int)f2bf(v.x) | ((unsigned int)f2bf(v.y) << 16);
      u.y = (unsigned int)f2bf(v.z) | ((unsigned int)f2bf(v.w) << 16);
      *(uint2*)(tile + row * 1536 + ((c4 * 8) ^ ((row & 7) << 4))) = u;
    }
  }
  __syncthreads();

  // ---- GEMM machinery (A from resident tile, B from packed frags, reg dbuf) ----
  const int sx0 = (lg * 16) ^ ((lr & 7) << 4);
  const unsigned char* baA0 = tile + lr * 1536 + sx0;
  const unsigned char* baA1 = tile + lr * 1536 + (sx0 ^ 64);
  const unsigned short* gB = Gpk + ((size_t)(wid * 6) * 24 * 64 + lane) * 8;
  const unsigned short* oB = Opk + ((size_t)(wid * 6) * 24 * 64 + lane) * 8;

  bf16x8 aF0[4], aF1[4];
  bf16x8 bP[12], bQ[12];

#define LOAD_B(BB, KT, BR) { _Pragma("unroll") for (int nt = 0; nt < 6; ++nt) { \
      BR[nt * 2 + 0] = *(const bf16x8*)((BB) + nt * 12288 + ((KT) * 2 + 0) * 512); \
      BR[nt * 2 + 1] = *(const bf16x8*)((BB) + nt * 12288 + ((KT) * 2 + 1) * 512); } }
#define RD_A(KT) { _Pragma("unroll") for (int mt = 0; mt < 4; ++mt) { \
      aF0[mt] = *(const bf16x8*)(baA0 + mt * 24576 + (KT) * 128); \
      aF1[mt] = *(const bf16x8*)(baA1 + mt * 24576 + (KT) * 128); } }
#define MM48(ACC, BR) { __builtin_amdgcn_s_setprio(1); \
    _Pragma("unroll") for (int mt = 0; mt < 4; ++mt) \
    _Pragma("unroll") for (int nt = 0; nt < 6; ++nt) { \
      ACC[mt][nt] = __builtin_amdgcn_mfma_f32_16x16x32_bf16(aF0[mt], BR[nt * 2 + 0], ACC[mt][nt], 0, 0, 0); \
      ACC[mt][nt] = __builtin_amdgcn_mfma_f32_16x16x32_bf16(aF1[mt], BR[nt * 2 + 1], ACC[mt][nt], 0, 0, 0); } \
    __builtin_amdgcn_s_setprio(0); }
#define GEMM_LOOP(BB, ACC) { \
    LOAD_B(BB, 0, bP); \
    _Pragma("unroll 1") \
    for (int kt = 0; kt < 10; kt += 2) { \
      LOAD_B(BB, kt + 1, bQ); RD_A(kt); LGKM(0); VMC(12); MM48(ACC, bP); \
      LOAD_B(BB, kt + 2, bP); RD_A(kt + 1); LGKM(0); VMC(12); MM48(ACC, bQ); \
    } \
    LOAD_B(BB, 11, bQ); RD_A(10); LGKM(0); VMC(12); MM48(ACC, bP); \
    RD_A(11); LGKM(0); VMC(0); MM48(ACC, bQ); }

  // ---- P1: gate GEMM: accG = x @ Gw^T (per wave: 64 rows x 96 cols) ----
  f32x4 accG[4][6];
#pragma unroll
  for (int mt = 0; mt < 4; ++mt)
#pragma unroll
    for (int nt = 0; nt < 6; ++nt) accG[mt][nt] = (f32x4){0, 0, 0, 0};
  GEMM_LOOP(gB, accG);

  // ---- P3: monarch (2x 32-row halves) + h combine + accO(residual+ob) init ----
  f32x4 accO[4][6];

#define MONARCH_HALF(H) { \
    /* stage1: wave handles k = wid*2 + kb; z32 -> scratch */ \
    _Pragma("unroll") for (int kb = 0; kb < 2; ++kb) { \
      const int k = wid * 2 + kb; \
      const unsigned short* wf = w1f + (size_t)(k * 6) * 512 + lane * 8; \
      bf16x8 w1b0 = *(const bf16x8*)(wf + 0 * 512); \
      bf16x8 w1b1 = *(const bf16x8*)(wf + 1 * 512); \
      bf16x8 w1b2 = *(const bf16x8*)(wf + 2 * 512); \
      bf16x8 w1b3 = *(const bf16x8*)(wf + 3 * 512); \
      bf16x8 w1b4 = *(const bf16x8*)(wf + 4 * 512); \
      bf16x8 w1b5 = *(const bf16x8*)(wf + 5 * 512); \
      _Pragma("unroll") for (int mtl = 0; mtl < 2; ++mtl) { \
        const int row = (H) * 32 + mtl * 16 + lr; \
        const int rsw = (lr & 7) << 4; \
        bf16x8 a0 = *(const bf16x8*)(tile + row * 1536 + ((k * 96 + lg * 16) ^ rsw)); \
        bf16x8 a1 = (bf16x8){0, 0, 0, 0, 0, 0, 0, 0}; \
        if (lg < 2) a1 = *(const bf16x8*)(tile + row * 1536 + ((k * 96 + 64 + lg * 16) ^ rsw)); \
        f32x4 c0 = {0,0,0,0}, c1 = {0,0,0,0}, c2 = {0,0,0,0}; \
        c0 = __builtin_amdgcn_mfma_f32_16x16x32_bf16(a0, w1b0, c0, 0, 0, 0); \
        c0 = __builtin_amdgcn_mfma_f32_16x16x32_bf16(a1, w1b1, c0, 0, 0, 0); \
        c1 = __builtin_amdgcn_mfma_f32_16x16x32_bf16(a0, w1b2, c1, 0, 0, 0); \
        c1 = __builtin_amdgcn_mfma_f32_16x16x32_bf16(a1, w1b3, c1, 0, 0, 0); \
        c2 = __builtin_amdgcn_mfma_f32_16x16x32_bf16(a0, w1b4, c2, 0, 0, 0); \
        c2 = __builtin_amdgcn_mfma_f32_16x16x32_bf16(a1, w1b5, c2, 0, 0, 0); \
        _Pragma("unroll") for (int i = 0; i < 4; ++i) { \
          int rl = mtl * 16 + lg * 4 + i; \
          int zsw = (rl & 7) << 4; \
          *(unsigned short*)(scratch + ((rl * 1536 + 0 * 512 + lr * 32 + k * 2) ^ zsw)) = f2bf(c0[i]); \
          *(unsigned short*)(scratch + ((rl * 1536 + 1 * 512 + lr * 32 + k * 2) ^ zsw)) = f2bf(c1[i]); \
          *(unsigned short*)(scratch + ((rl * 1536 + 2 * 512 + lr * 32 + k * 2) ^ zsw)) = f2bf(c2[i]); } } } \
    __syncthreads(); \
    /* stage2: wave handles q = wid*6 + qq (8 waves x 6 = 48); u packed in regs */ \
    { unsigned int upk[2][4][3]; \
    _Pragma("unroll") for (int qq = 0; qq < 6; ++qq) { \
      const int q = wid * 6 + qq; \
      bf16x8 bw = *(const bf16x8*)(w2f + (size_t)q * 512 + lane * 8); \
      _Pragma("unroll") for (int mtl = 0; mtl < 2; ++mtl) { \
        int rl = mtl * 16 + lr; \
        bf16x8 a = (bf16x8){0, 0, 0, 0, 0, 0, 0, 0}; \
        if (lg < 2) a = *(const bf16x8*)(scratch + ((rl * 1536 + q * 32 + lg * 16) ^ ((rl & 7) << 4))); \
        f32x4 c = {0, 0, 0, 0}; \
        c = __builtin_amdgcn_mfma_f32_16x16x32_bf16(a, bw, c, 0, 0, 0); \
        _Pragma("unroll") for (int i = 0; i < 4; ++i) { \
          unsigned int h = (unsigned int)f2bf(c[i]); \
          if (qq & 1) upk[mtl][i][qq >> 1] |= (h << 16); \
          else        upk[mtl][i][qq >> 1] = h; } } } \
    __syncthreads();  /* z reads done; scratch reusable */ \
    /* mixed32 row-major bf16 into scratch: u[rl][n = lr*48 + wid*6 + qq] */ \
    _Pragma("unroll") for (int mtl = 0; mtl < 2; ++mtl) \
    _Pragma("unroll") for (int i = 0; i < 4; ++i) { \
      int rl = mtl * 16 + lg * 4 + i; \
      int base = rl * 1536 + lr * 96 + wid * 12; \
      int msw = (rl & 7) << 4; \
      _Pragma("unroll") for (int p = 0; p < 3; ++p) \
        *(unsigned int*)(scratch + ((base + p * 4) ^ msw)) = upk[mtl][i][p]; } } \
    __syncthreads(); \
    /* accO init (residual + ob from tile/x) then h overwrites tile */ \
    _Pragma("unroll") for (int mtl = 0; mtl < 2; ++mtl) \
    _Pragma("unroll") for (int nt = 0; nt < 6; ++nt) \
    _Pragma("unroll") for (int i = 0; i < 4; ++i) { \
      int rl = mtl * 16 + lg * 4 + i; \
      int row = (H) * 32 + rl; \
      int colb = (wid * 96 + nt * 16 + lr) * 2; \
      float mval = bf2f(*(const unsigned short*)(scratch + ((rl * 1536 + colb) ^ ((rl & 7) << 4)))); \
      float g = accG[(H) * 2 + mtl][nt][i] + gbv[nt]; \
      float s = 1.0f / (1.0f + __expf(-g)); \
      unsigned char* tp = tile + row * 1536 + (colb ^ ((row & 7) << 4)); \
      accO[(H) * 2 + mtl][nt][i] = bf2f(*(const unsigned short*)tp) + obv[nt]; \
      *(unsigned short*)tp = f2bf(s * mval); } \
    __syncthreads(); }

  MONARCH_HALF(0)
  MONARCH_HALF(1)

  // ---- P4: out GEMM: accO += h @ Ow^T (tile now holds h) ----
  GEMM_LOOP(oB, accO);

  // ---- P5: LayerNorm + fp32 store ----
#pragma unroll
  for (int mt = 0; mt < 4; ++mt) {
#pragma unroll
    for (int i = 0; i < 4; ++i) {
      float s = 0.f, q = 0.f;
#pragma unroll
      for (int nt = 0; nt < 6; ++nt) { float v = accO[mt][nt][i]; s += v; q += v * v; }
#pragma unroll
      for (int off = 8; off >= 1; off >>= 1) {
        s += __shfl_xor(s, off);
        q += __shfl_xor(q, off);
      }
      if (lr == 0) {
        int rl = mt * 16 + lg * 4 + i;
        psum[rl][wid] = s; psq[rl][wid] = q;
      }
    }
  }
  __syncthreads();
#pragma unroll
  for (int mt = 0; mt < 4; ++mt) {
#pragma unroll
    for (int i = 0; i < 4; ++i) {
      int rl = mt * 16 + lg * 4 + i;
      float s = 0.f, q = 0.f;
#pragma unroll
      for (int w = 0; w < 8; ++w) { s += psum[rl][w]; q += psq[rl][w]; }
      float mu = s * (1.0f / 768.0f);
      float var = q * (1.0f / 768.0f) - mu * mu;
      var = var < 0.f ? 0.f : var;
      float rstd = rsqrtf(var + 1e-12f);
      size_t grow = m0 + rl;
#pragma unroll
      for (int nt = 0; nt < 6; ++nt) {
        int col = wid * 96 + nt * 16 + lr;
        out[grow * 768 + col] = (accO[mt][nt][i] - mu) * rstd * gamma[col] + beta[col];
      }
    }
  }
#undef LOAD_B
#undef RD_A
#undef MM48
#undef GEMM_LOOP
#undef MONARCH_HALF
}

// ---------------- launch ----------------
extern "C" void kernel_launch(void* const* d_in, const int* in_sizes, int n_in,
                              void* d_out, int out_size, void* d_ws, size_t ws_size,
                              hipStream_t stream) {
  const float* x   = (const float*)d_in[0];
  const float* w1  = (const float*)d_in[1];
  const float* w2  = (const float*)d_in[2];
  const float* gw  = (const float*)d_in[3];
  const float* gb  = (const float*)d_in[4];
  const float* ow  = (const float*)d_in[5];
  const float* ob  = (const float*)d_in[6];
  const float* gam = (const float*)d_in[7];
  const float* bet = (const float*)d_in[8];
  float* out = (float*)d_out;

  char* ws = (char*)d_ws;
  unsigned short* Gpk = (unsigned short*)(ws);                   // 1,179,648 B
  unsigned short* Opk = (unsigned short*)(ws + 1179648);         // 1,179,648 B
  unsigned short* w1f = (unsigned short*)(ws + 2359296);         //    98,304 B
  unsigned short* w2f = (unsigned short*)(ws + 2457600);         //    49,152 B

  prep_kernel<<<612, 256, 0, stream>>>(gw, ow, w1, w2, Gpk, Opk, w1f, w2f);
  fused_kernel<<<256, 512, 0, stream>>>(x, Gpk, Opk, w1f, w2f, gb, ob, gam, bet, out);
}